// Round 1
// baseline (551.825 us; speedup 1.0000x reference)
//
#include <hip/hip_runtime.h>
#include <hip/hip_bf16.h>
#include <math.h>

// Problem constants (fixed by setup_inputs)
#define B_   64
#define C_   5
#define H_   50
#define S_   32
#define E_   768
#define D_   768
#define K_   5
#define RC_  (B_*C_)          // 320 candidate rows
#define RH_  (B_*H_)          // 3200 history rows
#define RT_  (RC_+RH_)        // 3520 total projected rows
#define CHUNK_ (S_*E_)        // 24576 elements per (b,c,k) slab
#define NCHUNK_ (B_*C_*K_)    // 1600 slabs
#define OUT_SEL_ ((size_t)B_*C_*K_*S_*E_)   // 39321600 elements, then mask region

// ws layout (bytes)
#define WS_P_OFF    0
#define WS_P_BYTES  ((size_t)RT_*D_*4)          // 10,813,440
#define WS_IDX_OFF  (WS_P_BYTES)                // int[1600]
#define WS_FLAG_OFF (WS_P_BYTES + 6400)

// ---------------- dtype helpers ----------------
__device__ __forceinline__ void load4f(const float* p, float* v) {
    float4 x = *(const float4*)p;
    v[0] = x.x; v[1] = x.y; v[2] = x.z; v[3] = x.w;
}
__device__ __forceinline__ void load4f(const __hip_bfloat16* p, float* v) {
    ushort4 x = *(const ushort4*)p;
    v[0] = __uint_as_float(((unsigned)x.x) << 16);
    v[1] = __uint_as_float(((unsigned)x.y) << 16);
    v[2] = __uint_as_float(((unsigned)x.z) << 16);
    v[3] = __uint_as_float(((unsigned)x.w) << 16);
}
__device__ __forceinline__ void store_elem(float v, float* p) { *p = v; }
__device__ __forceinline__ void store_elem(float v, __hip_bfloat16* p) { *p = __float2bfloat16(v); }

// ---------------- dtype detection ----------------
// If inputs are bf16: low 16 bits of each 32-bit word = an even-index bf16 of
// N(0,1) data -> |x| in a sane range essentially always.
// If inputs are f32: low 16 bits = low mantissa bits -> as-bf16 exponent is
// ~uniform random -> only ~24% land in the sane band.
__global__ void detect_kernel(const unsigned int* words, int* flag) {
    int l = threadIdx.x;
    unsigned int w = words[l];
    float f = __uint_as_float((w & 0xffffu) << 16);
    float a = fabsf(f);
    bool plausible = (a > 9.3e-10f) && (a < 1.0e9f);
    unsigned long long m = __ballot(plausible);
    if (l == 0) *flag = (__popcll(m) >= 48) ? 1 : 0;   // 1 = bf16, 0 = f32
}

// ---------------- projection GEMM ----------------
// P[r][j] = sum_d X[r][d] * W[j][d] + bias[j], f32 accumulate.
// X row r: r < RC_ -> cdd_repr, else his_repr. 64x64 tile, BK=16, 4x4/thread.
template <typename T, int WANT>
__global__ __launch_bounds__(256) void gemm_kernel(
    const int* __restrict__ flag,
    const T* __restrict__ cdd, const T* __restrict__ his,
    const T* __restrict__ W, const T* __restrict__ bias,
    float* __restrict__ P)
{
    if (*flag != WANT) return;
    __shared__ float As[16][64];
    __shared__ float Bs[16][64];

    const int t    = threadIdx.x;
    const int ty4  = (t >> 4) * 4;   // 0..60, row offset in tile
    const int tx4  = (t & 15) * 4;   // 0..60, col offset in tile
    const int row0 = blockIdx.y * 64;
    const int col0 = blockIdx.x * 64;

    const int lrow = t >> 2;         // 0..63 (tile row this thread stages)
    const int ks4  = (t & 3) * 4;    // k sub-offset 0,4,8,12

    const int grow = row0 + lrow;
    const T* arow = (grow < RC_) ? (cdd + (size_t)grow * D_)
                                 : (his + (size_t)(grow - RC_) * D_);
    const T* brow = W + (size_t)(col0 + lrow) * D_;

    float acc[4][4] = {};

    for (int k0 = 0; k0 < D_; k0 += 16) {
        float av[4], bv[4];
        load4f(arow + k0 + ks4, av);
        load4f(brow + k0 + ks4, bv);
        __syncthreads();
        #pragma unroll
        for (int i = 0; i < 4; i++) {
            As[ks4 + i][lrow] = av[i];
            Bs[ks4 + i][lrow] = bv[i];
        }
        __syncthreads();
        #pragma unroll
        for (int kk = 0; kk < 16; kk++) {
            float4 a4 = *(const float4*)&As[kk][ty4];
            float4 b4 = *(const float4*)&Bs[kk][tx4];
            float aa[4] = {a4.x, a4.y, a4.z, a4.w};
            float bb[4] = {b4.x, b4.y, b4.z, b4.w};
            #pragma unroll
            for (int i = 0; i < 4; i++)
                #pragma unroll
                for (int j = 0; j < 4; j++)
                    acc[i][j] += aa[i] * bb[j];
        }
    }

    float bj[4];
    load4f(bias + col0 + tx4, bj);
    #pragma unroll
    for (int i = 0; i < 4; i++) {
        size_t rbase = (size_t)(row0 + ty4 + i) * D_ + col0 + tx4;
        #pragma unroll
        for (int j = 0; j < 4; j++)
            P[rbase + j] = acc[i][j] + bj[j];
    }
}

// ---------------- attn + top-k ----------------
// One block per (b,c). attn[n] = dot(Pc,Ph[n]) / max(|Ph[n]|,1e-12)
// (dividing by |Pc| is a positive common factor -> rank-preserving).
__global__ __launch_bounds__(256) void attn_topk_kernel(
    const float* __restrict__ P, const int* __restrict__ his_mask,
    int* __restrict__ idx_out)
{
    const int blk = blockIdx.x;        // 0..319 = b*C_+c
    const int b   = blk / C_;
    __shared__ float pc[D_];
    __shared__ float attn_s[H_];

    const int t = threadIdx.x;
    for (int d = t; d < D_; d += 256) pc[d] = P[(size_t)blk * D_ + d];
    __syncthreads();

    const int wave = t >> 6, lane = t & 63;
    const float* ph_base = P + (size_t)(RC_ + b * H_) * D_;

    for (int n = wave; n < H_; n += 4) {
        const float* ph = ph_base + (size_t)n * D_;
        float dot = 0.f, nn = 0.f;
        #pragma unroll
        for (int j = 0; j < D_ / 64; j++) {
            float v = ph[lane + 64 * j];
            dot += pc[lane + 64 * j] * v;
            nn  += v * v;
        }
        #pragma unroll
        for (int off = 32; off; off >>= 1) {
            dot += __shfl_xor(dot, off, 64);
            nn  += __shfl_xor(nn,  off, 64);
        }
        if (lane == 0) {
            float norm = sqrtf(nn);
            if (norm < 1e-12f) norm = 1e-12f;
            float a = dot / norm;
            bool valid = (his_mask[b * H_ + n] != 0) || (n < K_);
            attn_s[n] = valid ? a : -INFINITY;
        }
    }
    __syncthreads();

    if (t == 0) {
        // top-K, ties -> lowest index (matches jax.lax.top_k)
        unsigned long long used = 0ull;
        for (int k = 0; k < K_; k++) {
            int bi = -1; float best = 0.f;
            for (int n = 0; n < H_; n++) {
                if ((used >> n) & 1ull) continue;
                if (bi < 0 || attn_s[n] > best) { bi = n; best = attn_s[n]; }
            }
            used |= (1ull << bi);
            idx_out[blk * K_ + k] = bi;
        }
    }
}

// ---------------- gather ----------------
template <typename T, int WANT>
__global__ __launch_bounds__(256) void gather_kernel(
    const int* __restrict__ flag, const int* __restrict__ idx,
    const T* __restrict__ his_emb, const int* __restrict__ his_attn_mask,
    T* __restrict__ out)
{
    if (*flag != WANT) return;
    const int chunk = blockIdx.x;          // 0..1599 = (b*C_+c)*K_+k
    const int b = chunk / (C_ * K_);
    const int n = idx[chunk];

    const T* src = his_emb + (size_t)(b * H_ + n) * CHUNK_;
    T* dst = out + (size_t)chunk * CHUNK_;

    constexpr int VB = (int)(sizeof(uint4) / sizeof(T));  // 8 (bf16) / 4 (f32)
    const uint4* s4 = (const uint4*)src;
    uint4* d4 = (uint4*)dst;
    const int nvec = CHUNK_ / VB;
    const int t = threadIdx.x;
    for (int i = t; i < nvec; i += 256) d4[i] = s4[i];

    if (t < S_) {
        float mv = (float)his_attn_mask[(b * H_ + n) * S_ + t];
        store_elem(mv, out + OUT_SEL_ + (size_t)chunk * S_ + t);
    }
}

// ---------------- launch ----------------
extern "C" void kernel_launch(void* const* d_in, const int* in_sizes, int n_in,
                              void* d_out, int out_size, void* d_ws, size_t ws_size,
                              hipStream_t stream) {
    const void* cdd  = d_in[0];
    const void* his  = d_in[1];
    const void* emb  = d_in[2];
    const int* attn_mask = (const int*)d_in[3];  // [B,H,S]
    const int* his_mask  = (const int*)d_in[4];  // [B,H,1]
    const void* W    = d_in[5];
    const void* bias = d_in[6];

    char* ws  = (char*)d_ws;
    float* P  = (float*)(ws + WS_P_OFF);
    int* idx  = (int*)(ws + WS_IDX_OFF);
    int* flag = (int*)(ws + WS_FLAG_OFF);

    detect_kernel<<<1, 64, 0, stream>>>((const unsigned int*)cdd, flag);

    dim3 ggrid(D_ / 64, RT_ / 64);  // (12, 55)
    gemm_kernel<__hip_bfloat16, 1><<<ggrid, 256, 0, stream>>>(
        flag, (const __hip_bfloat16*)cdd, (const __hip_bfloat16*)his,
        (const __hip_bfloat16*)W, (const __hip_bfloat16*)bias, P);
    gemm_kernel<float, 0><<<ggrid, 256, 0, stream>>>(
        flag, (const float*)cdd, (const float*)his,
        (const float*)W, (const float*)bias, P);

    attn_topk_kernel<<<RC_, 256, 0, stream>>>(P, his_mask, idx);

    gather_kernel<__hip_bfloat16, 1><<<NCHUNK_, 256, 0, stream>>>(
        flag, idx, (const __hip_bfloat16*)emb, attn_mask, (__hip_bfloat16*)d_out);
    gather_kernel<float, 0><<<NCHUNK_, 256, 0, stream>>>(
        flag, idx, (const float*)emb, attn_mask, (float*)d_out);
}